// Round 2
// baseline (62.410 us; speedup 1.0000x reference)
//
#include <hip/hip_runtime.h>

// SequentialSparsemax: (8, 16, 262144) f32.
// pass1: sparsemax over 16 instruments at every (b, t).
// pass2: sparsemax over each 64-sample frame per (b, inst).
// Fused, software-pipelined: each 64-thread (1-wave) block handles 4
// consecutive (16 inst x 256 time) tiles; next tile's global loads are
// issued before current tile's compute so sort work hides HBM latency.
// LDS fences are lgkm-only (single-wave block) so prefetch loads stay
// in flight across the LDS transpose.

#define T_DIM   262144
#define N_INST  16
#define B_DIM   8
#define CHUNK   256                   // time samples per wave-tile (4 frames)
#define NCHUNK  (T_DIM / CHUNK)       // 1024
#define TPB_TILES 4                   // tiles per block (consecutive chunks)
#define GRID    (B_DIM * NCHUNK / TPB_TILES)  // 2048

// One bitonic stage; K,S compile-time so `desc` folds and all indices are
// constants after unroll (registers, no scratch).
template<int N, int K, int S>
__device__ __forceinline__ void bstage(float (&a)[N]) {
#pragma unroll
  for (int i = 0; i < N; ++i) {
    const int l = i ^ S;
    if (l > i) {
      const float x = a[i], y = a[l];
      const float hi = fmaxf(x, y), lo = fminf(x, y);
      const bool desc = ((i & K) == 0);
      a[i] = desc ? hi : lo;
      a[l] = desc ? lo : hi;
    }
  }
}

__device__ __forceinline__ void sort_desc16(float (&a)[16]) {
  bstage<16, 2, 1>(a);
  bstage<16, 4, 2>(a);  bstage<16, 4, 1>(a);
  bstage<16, 8, 4>(a);  bstage<16, 8, 2>(a);  bstage<16, 8, 1>(a);
  bstage<16, 16, 8>(a); bstage<16, 16, 4>(a); bstage<16, 16, 2>(a); bstage<16, 16, 1>(a);
}

__device__ __forceinline__ void sort_desc64(float (&a)[64]) {
  bstage<64, 2, 1>(a);
  bstage<64, 4, 2>(a);   bstage<64, 4, 1>(a);
  bstage<64, 8, 4>(a);   bstage<64, 8, 2>(a);   bstage<64, 8, 1>(a);
  bstage<64, 16, 8>(a);  bstage<64, 16, 4>(a);  bstage<64, 16, 2>(a);  bstage<64, 16, 1>(a);
  bstage<64, 32, 16>(a); bstage<64, 32, 8>(a);  bstage<64, 32, 4>(a);  bstage<64, 32, 2>(a);  bstage<64, 32, 1>(a);
  bstage<64, 64, 32>(a); bstage<64, 64, 16>(a); bstage<64, 64, 8>(a);  bstage<64, 64, 4>(a);  bstage<64, 64, 2>(a);  bstage<64, 64, 1>(a);
}

// z must be sorted descending. Mirrors the reference exactly:
// support_k = 1 + (k+1)*z_k > cs_k (prefix-true); tau = (cs_{k*} - 1)/k*.
template<int N>
__device__ __forceinline__ float sparsemax_tau(const float (&z)[N]) {
  float cs = 0.0f, cs_sel = 0.0f, k_sel = 1.0f;
#pragma unroll
  for (int k = 0; k < N; ++k) {
    cs += z[k];
    const bool sup = fmaf((float)(k + 1), z[k], 1.0f) > cs;
    k_sel = sup ? (float)(k + 1) : k_sel;
    cs_sel = sup ? cs : cs_sel;
  }
  return (cs_sel - 1.0f) / k_sel;
}

// lgkm-only fence: orders this wave's LDS writes/reads without draining
// vmcnt (prefetch loads stay in flight). Single-wave block => no s_barrier.
__device__ __forceinline__ void lds_fence() {
  asm volatile("s_waitcnt lgkmcnt(0)" ::: "memory");
  __builtin_amdgcn_sched_barrier(0);
}

__device__ __forceinline__ void load_tile(const float* __restrict__ p,
                                          float (&v)[N_INST][4]) {
#pragma unroll
  for (int i = 0; i < N_INST; ++i) {
    const float4 q = *reinterpret_cast<const float4*>(p + (size_t)i * T_DIM);
    v[i][0] = q.x; v[i][1] = q.y; v[i][2] = q.z; v[i][3] = q.w;
  }
}

__global__ __launch_bounds__(64) void seq_sparsemax_kernel(
    const float* __restrict__ in, float* __restrict__ out) {
  __shared__ float tile[N_INST * CHUNK];  // 16 KiB

  const int lane = threadIdx.x;                 // 0..63
  const int b    = blockIdx.x >> 8;             // 256 blocks per batch
  const int c0   = (blockIdx.x & 255) * TPB_TILES;
  const size_t base0 = (size_t)b * N_INST * T_DIM + (size_t)c0 * CHUNK + 4 * lane;

  float A[N_INST][4], Bf[N_INST][4];
  load_tile(in + base0, A);

#pragma unroll 1
  for (int k = 0; k < TPB_TILES; ++k) {
    // ---- prefetch next tile (in flight across all compute below) ----
    if (k + 1 < TPB_TILES) load_tile(in + base0 + (size_t)(k + 1) * CHUNK, Bf);

    // ---- pass 1: sparsemax over instruments at each of this lane's 4 times ----
#pragma unroll
    for (int j = 0; j < 4; ++j) {
      float z[N_INST];
#pragma unroll
      for (int i = 0; i < N_INST; ++i) z[i] = A[i][j];
      sort_desc16(z);
      const float tau = sparsemax_tau(z);
#pragma unroll
      for (int i = 0; i < N_INST; ++i) A[i][j] = fmaxf(A[i][j] - tau, 0.0f);
    }

    // ---- stage to LDS, XOR-swizzled; WAR fence vs prev iter's reads ----
    lds_fence();
#pragma unroll
    for (int i = 0; i < N_INST; ++i) {
      const int fi = i * CHUNK + ((4 * lane) ^ ((i & 7) << 2));
      *reinterpret_cast<float4*>(&tile[fi]) =
          make_float4(A[i][0], A[i][1], A[i][2], A[i][3]);
    }
    lds_fence();  // RAW: writes visible before pass-2 reads

    // ---- pass 2: lane = one (inst, frame) row of 64; order-free gather ----
    const int i2 = lane >> 2;   // inst
    const int f2 = lane & 3;    // frame within chunk
    float w[64];
#pragma unroll
    for (int j = 0; j < 16; ++j) {
      const int fi = i2 * CHUNK + ((f2 * 64 + 4 * j) ^ ((i2 & 7) << 2));
      const float4 q = *reinterpret_cast<const float4*>(&tile[fi]);
      w[4 * j + 0] = q.x; w[4 * j + 1] = q.y; w[4 * j + 2] = q.z; w[4 * j + 3] = q.w;
    }
    sort_desc64(w);
    const float tau2 = sparsemax_tau(w);

    // ---- broadcast row-taus to phase-1 layout; coalesced float4 stores ----
    const int f1 = lane >> 4;   // this lane's frame
    float* outp = out + base0 + (size_t)k * CHUNK;
#pragma unroll
    for (int i = 0; i < N_INST; ++i) {
      const int srclane = i * 4 + f1;  // pass-2 lane holding tau for (i, f1)
      const float taui = __int_as_float(
          __builtin_amdgcn_ds_bpermute(srclane << 2, __float_as_int(tau2)));
      const int fi = i * CHUNK + ((4 * lane) ^ ((i & 7) << 2));
      const float4 q = *reinterpret_cast<const float4*>(&tile[fi]);
      float4 o;
      o.x = fmaxf(q.x - taui, 0.0f);
      o.y = fmaxf(q.y - taui, 0.0f);
      o.z = fmaxf(q.z - taui, 0.0f);
      o.w = fmaxf(q.w - taui, 0.0f);
      *reinterpret_cast<float4*>(outp + (size_t)i * T_DIM) = o;
    }

    // ---- rotate prefetched tile into A (waits its vmcnt here, latency
    //      already covered by this iteration's compute) ----
    if (k + 1 < TPB_TILES) {
#pragma unroll
      for (int i = 0; i < N_INST; ++i)
#pragma unroll
        for (int j = 0; j < 4; ++j) A[i][j] = Bf[i][j];
    }
  }
}

extern "C" void kernel_launch(void* const* d_in, const int* in_sizes, int n_in,
                              void* d_out, int out_size, void* d_ws, size_t ws_size,
                              hipStream_t stream) {
  const float* in = (const float*)d_in[0];
  float* out = (float*)d_out;
  seq_sparsemax_kernel<<<GRID, 64, 0, stream>>>(in, out);
}

// Round 3
// 61.012 us; speedup vs baseline: 1.0229x; 1.0229x over previous
//
#include <hip/hip_runtime.h>

// SequentialSparsemax: (8, 16, 262144) f32.
// pass1: sparsemax over 16 instruments at every (b, t).
// pass2: sparsemax over each 64-sample frame per (b, inst).
// Fused, one wave per (16 inst x 256 time) tile.
// LDS cut to 12 KiB (occupancy cap 10 -> 13 blocks/CU) via 2-round
// transpose: round A stages insts 0..11 (lanes 0..47 gather their rows),
// round B overwrites slots 0..3 with insts 12..15 (lanes 48..63 gather).
// Phase 3 reads insts 0..3 from registers, the rest from LDS.

#define T_DIM   262144
#define N_INST  16
#define B_DIM   8
#define CHUNK   256                   // time samples per wave-tile (4 frames)
#define NCHUNK  (T_DIM / CHUNK)       // 1024
#define NSLOT   12                    // LDS slots (12 KiB)

// One bitonic stage; K,S compile-time so `desc` folds and all indices are
// constants after unroll (registers, no scratch).
template<int N, int K, int S>
__device__ __forceinline__ void bstage(float (&a)[N]) {
#pragma unroll
  for (int i = 0; i < N; ++i) {
    const int l = i ^ S;
    if (l > i) {
      const float x = a[i], y = a[l];
      const float hi = fmaxf(x, y), lo = fminf(x, y);
      const bool desc = ((i & K) == 0);
      a[i] = desc ? hi : lo;
      a[l] = desc ? lo : hi;
    }
  }
}

__device__ __forceinline__ void sort_desc16(float (&a)[16]) {
  bstage<16, 2, 1>(a);
  bstage<16, 4, 2>(a);  bstage<16, 4, 1>(a);
  bstage<16, 8, 4>(a);  bstage<16, 8, 2>(a);  bstage<16, 8, 1>(a);
  bstage<16, 16, 8>(a); bstage<16, 16, 4>(a); bstage<16, 16, 2>(a); bstage<16, 16, 1>(a);
}

__device__ __forceinline__ void sort_desc64(float (&a)[64]) {
  bstage<64, 2, 1>(a);
  bstage<64, 4, 2>(a);   bstage<64, 4, 1>(a);
  bstage<64, 8, 4>(a);   bstage<64, 8, 2>(a);   bstage<64, 8, 1>(a);
  bstage<64, 16, 8>(a);  bstage<64, 16, 4>(a);  bstage<64, 16, 2>(a);  bstage<64, 16, 1>(a);
  bstage<64, 32, 16>(a); bstage<64, 32, 8>(a);  bstage<64, 32, 4>(a);  bstage<64, 32, 2>(a);  bstage<64, 32, 1>(a);
  bstage<64, 64, 32>(a); bstage<64, 64, 16>(a); bstage<64, 64, 8>(a);  bstage<64, 64, 4>(a);  bstage<64, 64, 2>(a);  bstage<64, 64, 1>(a);
}

// z must be sorted descending. Mirrors the reference exactly:
// support_k = 1 + (k+1)*z_k > cs_k (prefix-true); tau = (cs_{k*} - 1)/k*.
template<int N>
__device__ __forceinline__ float sparsemax_tau(const float (&z)[N]) {
  float cs = 0.0f, cs_sel = 0.0f, k_sel = 1.0f;
#pragma unroll
  for (int k = 0; k < N; ++k) {
    cs += z[k];
    const bool sup = fmaf((float)(k + 1), z[k], 1.0f) > cs;
    k_sel = sup ? (float)(k + 1) : k_sel;
    cs_sel = sup ? cs : cs_sel;
  }
  return (cs_sel - 1.0f) / k_sel;
}

// lgkm-only fence: orders this wave's LDS ops without draining vmcnt.
// Single-wave block => no s_barrier needed.
__device__ __forceinline__ void lds_fence() {
  asm volatile("s_waitcnt lgkmcnt(0)" ::: "memory");
  __builtin_amdgcn_sched_barrier(0);
}

__global__ __launch_bounds__(64, 4) void seq_sparsemax_kernel(
    const float* __restrict__ in, float* __restrict__ out) {
  __shared__ float tile[NSLOT * CHUNK];  // 12 KiB

  const int lane  = threadIdx.x;          // 0..63
  const int b     = blockIdx.x >> 10;     // / NCHUNK
  const int chunk = blockIdx.x & (NCHUNK - 1);
  const size_t base = (size_t)b * N_INST * T_DIM + (size_t)chunk * CHUNK + 4 * lane;

  // ---- load: A[i][j] = in[b, i, t0 + 4*lane + j], coalesced float4 ----
  float A[N_INST][4];
#pragma unroll
  for (int i = 0; i < N_INST; ++i) {
    const float4 q = *reinterpret_cast<const float4*>(in + base + (size_t)i * T_DIM);
    A[i][0] = q.x; A[i][1] = q.y; A[i][2] = q.z; A[i][3] = q.w;
  }

  // ---- pass 1: sparsemax over instruments at each of this lane's 4 times ----
#pragma unroll
  for (int j = 0; j < 4; ++j) {
    float z[N_INST];
#pragma unroll
    for (int i = 0; i < N_INST; ++i) z[i] = A[i][j];
    sort_desc16(z);
    const float tau = sparsemax_tau(z);
#pragma unroll
    for (int i = 0; i < N_INST; ++i) A[i][j] = fmaxf(A[i][j] - tau, 0.0f);
  }

  // slot s swizzle: float index = s*CHUNK + (t ^ ((s&7)<<2))
  const int wt = 4 * lane;  // this lane's time offset within the tile

  // ---- round A: stage insts 0..11 into slots 0..11 ----
#pragma unroll
  for (int s = 0; s < NSLOT; ++s) {
    const int fi = s * CHUNK + (wt ^ ((s & 7) << 2));
    *reinterpret_cast<float4*>(&tile[fi]) =
        make_float4(A[s][0], A[s][1], A[s][2], A[s][3]);
  }
  lds_fence();  // RAW

  const int i2 = lane >> 2;   // row's inst (0..15)
  const int f2 = lane & 3;    // row's frame within chunk
  float w[64];
  if (lane < 48) {            // rows for insts 0..11
#pragma unroll
    for (int j = 0; j < 16; ++j) {
      const int fi = i2 * CHUNK + ((f2 * 64 + 4 * j) ^ ((i2 & 7) << 2));
      const float4 q = *reinterpret_cast<const float4*>(&tile[fi]);
      w[4 * j + 0] = q.x; w[4 * j + 1] = q.y; w[4 * j + 2] = q.z; w[4 * j + 3] = q.w;
    }
  }
  lds_fence();  // WAR: round-A reads complete before slots 0..3 overwritten

  // ---- round B: insts 12..15 overwrite slots 0..3 ----
#pragma unroll
  for (int i = 12; i < 16; ++i) {
    const int s = i - 12;
    const int fi = s * CHUNK + (wt ^ ((s & 7) << 2));
    *reinterpret_cast<float4*>(&tile[fi]) =
        make_float4(A[i][0], A[i][1], A[i][2], A[i][3]);
  }
  lds_fence();  // RAW
  if (lane >= 48) {           // rows for insts 12..15
    const int s = i2 - 12;
#pragma unroll
    for (int j = 0; j < 16; ++j) {
      const int fi = s * CHUNK + ((f2 * 64 + 4 * j) ^ ((s & 7) << 2));
      const float4 q = *reinterpret_cast<const float4*>(&tile[fi]);
      w[4 * j + 0] = q.x; w[4 * j + 1] = q.y; w[4 * j + 2] = q.z; w[4 * j + 3] = q.w;
    }
  }

  // ---- pass 2: each lane sorts its (inst, frame) row of 64 ----
  sort_desc64(w);
  const float tau2 = sparsemax_tau(w);

  // ---- phase 3: broadcast row-taus; sources: regs (i<4) or LDS; store ----
  const int f1 = lane >> 4;   // this lane's frame
#pragma unroll
  for (int i = 0; i < N_INST; ++i) {
    const int srclane = i * 4 + f1;  // pass-2 lane holding tau for (i, f1)
    const float taui = __int_as_float(
        __builtin_amdgcn_ds_bpermute(srclane << 2, __float_as_int(tau2)));
    float4 q;
    if (i < 4) {
      q = make_float4(A[i][0], A[i][1], A[i][2], A[i][3]);  // kept in regs
    } else {
      const int s = (i < 12) ? i : (i - 12);
      const int fi = s * CHUNK + (wt ^ ((s & 7) << 2));
      q = *reinterpret_cast<const float4*>(&tile[fi]);
    }
    float4 o;
    o.x = fmaxf(q.x - taui, 0.0f);
    o.y = fmaxf(q.y - taui, 0.0f);
    o.z = fmaxf(q.z - taui, 0.0f);
    o.w = fmaxf(q.w - taui, 0.0f);
    *reinterpret_cast<float4*>(out + base + (size_t)i * T_DIM) = o;
  }
}

extern "C" void kernel_launch(void* const* d_in, const int* in_sizes, int n_in,
                              void* d_out, int out_size, void* d_ws, size_t ws_size,
                              hipStream_t stream) {
  const float* in = (const float*)d_in[0];
  float* out = (float*)d_out;
  const int grid = B_DIM * NCHUNK;  // 8192 waves, one tile each
  seq_sparsemax_kernel<<<grid, 64, 0, stream>>>(in, out);
}

// Round 4
// 53.565 us; speedup vs baseline: 1.1651x; 1.1390x over previous
//
#include <hip/hip_runtime.h>

// SequentialSparsemax: (8, 16, 262144) f32.
// pass1: sparsemax over 16 instruments at every (b, t).
// pass2: sparsemax over each 64-sample frame per (b, inst).
// Fused; one wave per (16 inst x 256 time) tile; 4 independent waves per
// 256-thread workgroup (separate 12 KiB LDS slices, per-wave lgkm fences,
// no block barrier) to cut workgroup count 8192 -> 2048.
// tau via max-identity: tau = max_k (cs_k - 1)/k over descending-sorted z
// (h(k) rises exactly while the support condition holds, falls after).

#define T_DIM   262144
#define N_INST  16
#define B_DIM   8
#define CHUNK   256                   // time samples per wave-tile (4 frames)
#define NCHUNK  (T_DIM / CHUNK)       // 1024
#define NSLOT   12                    // LDS slots per wave (12 KiB)
#define WPB     4                     // independent waves per block

// One bitonic stage; K,S compile-time so `desc` folds and all indices are
// constants after unroll (registers, no scratch).
template<int N, int K, int S>
__device__ __forceinline__ void bstage(float (&a)[N]) {
#pragma unroll
  for (int i = 0; i < N; ++i) {
    const int l = i ^ S;
    if (l > i) {
      const float x = a[i], y = a[l];
      const float hi = fmaxf(x, y), lo = fminf(x, y);
      const bool desc = ((i & K) == 0);
      a[i] = desc ? hi : lo;
      a[l] = desc ? lo : hi;
    }
  }
}

__device__ __forceinline__ void sort_desc16(float (&a)[16]) {
  bstage<16, 2, 1>(a);
  bstage<16, 4, 2>(a);  bstage<16, 4, 1>(a);
  bstage<16, 8, 4>(a);  bstage<16, 8, 2>(a);  bstage<16, 8, 1>(a);
  bstage<16, 16, 8>(a); bstage<16, 16, 4>(a); bstage<16, 16, 2>(a); bstage<16, 16, 1>(a);
}

__device__ __forceinline__ void sort_desc64(float (&a)[64]) {
  bstage<64, 2, 1>(a);
  bstage<64, 4, 2>(a);   bstage<64, 4, 1>(a);
  bstage<64, 8, 4>(a);   bstage<64, 8, 2>(a);   bstage<64, 8, 1>(a);
  bstage<64, 16, 8>(a);  bstage<64, 16, 4>(a);  bstage<64, 16, 2>(a);  bstage<64, 16, 1>(a);
  bstage<64, 32, 16>(a); bstage<64, 32, 8>(a);  bstage<64, 32, 4>(a);  bstage<64, 32, 2>(a);  bstage<64, 32, 1>(a);
  bstage<64, 64, 32>(a); bstage<64, 64, 16>(a); bstage<64, 64, 8>(a);  bstage<64, 64, 4>(a);  bstage<64, 64, 2>(a);  bstage<64, 64, 1>(a);
}

// z sorted descending. tau = max_k (cs_k - 1)/k  (equals the reference's
// (cs_{k*}-1)/k*: h(k) increases iff the support condition holds at k,
// support is prefix-true, so the max is attained exactly at k*).
template<int N>
__device__ __forceinline__ float sparsemax_tau(const float (&z)[N]) {
  float cs = z[0];
  float tau = cs - 1.0f;  // k = 1
#pragma unroll
  for (int k = 1; k < N; ++k) {
    cs += z[k];
    tau = fmaxf(tau, (cs - 1.0f) * (1.0f / (float)(k + 1)));
  }
  return tau;
}

// lgkm-only fence: orders this wave's own-LDS ops without draining vmcnt.
// Waves within the block touch disjoint LDS slices => no s_barrier.
__device__ __forceinline__ void lds_fence() {
  asm volatile("s_waitcnt lgkmcnt(0)" ::: "memory");
  __builtin_amdgcn_sched_barrier(0);
}

__global__ __launch_bounds__(256) void seq_sparsemax_kernel(
    const float* __restrict__ in, float* __restrict__ out) {
  __shared__ float lds[WPB * NSLOT * CHUNK];  // 48 KiB

  const int lane = threadIdx.x & 63;
  const int wave = threadIdx.x >> 6;
  float* __restrict__ tile = &lds[wave * NSLOT * CHUNK];

  const int tid   = blockIdx.x * WPB + wave;   // tile index 0..8191
  const int b     = tid >> 10;                 // / NCHUNK
  const int chunk = tid & (NCHUNK - 1);
  const size_t base = (size_t)b * N_INST * T_DIM + (size_t)chunk * CHUNK + 4 * lane;

  // ---- load: A[i][j] = in[b, i, t0 + 4*lane + j], coalesced float4 ----
  float A[N_INST][4];
#pragma unroll
  for (int i = 0; i < N_INST; ++i) {
    const float4 q = *reinterpret_cast<const float4*>(in + base + (size_t)i * T_DIM);
    A[i][0] = q.x; A[i][1] = q.y; A[i][2] = q.z; A[i][3] = q.w;
  }

  // ---- pass 1: sparsemax over instruments at each of this lane's 4 times ----
#pragma unroll
  for (int j = 0; j < 4; ++j) {
    float z[N_INST];
#pragma unroll
    for (int i = 0; i < N_INST; ++i) z[i] = A[i][j];
    sort_desc16(z);
    const float tau = sparsemax_tau(z);
#pragma unroll
    for (int i = 0; i < N_INST; ++i) A[i][j] = fmaxf(A[i][j] - tau, 0.0f);
  }

  // slot s swizzle: float index = s*CHUNK + (t ^ ((s&7)<<2))
  const int wt = 4 * lane;  // this lane's time offset within the tile

  // ---- round A: stage insts 0..11 into slots 0..11 ----
#pragma unroll
  for (int s = 0; s < NSLOT; ++s) {
    const int fi = s * CHUNK + (wt ^ ((s & 7) << 2));
    *reinterpret_cast<float4*>(&tile[fi]) =
        make_float4(A[s][0], A[s][1], A[s][2], A[s][3]);
  }
  lds_fence();  // RAW

  const int i2 = lane >> 2;   // row's inst (0..15)
  const int f2 = lane & 3;    // row's frame within chunk
  float w[64];
  if (lane < 48) {            // rows for insts 0..11
#pragma unroll
    for (int j = 0; j < 16; ++j) {
      const int fi = i2 * CHUNK + ((f2 * 64 + 4 * j) ^ ((i2 & 7) << 2));
      const float4 q = *reinterpret_cast<const float4*>(&tile[fi]);
      w[4 * j + 0] = q.x; w[4 * j + 1] = q.y; w[4 * j + 2] = q.z; w[4 * j + 3] = q.w;
    }
  }
  lds_fence();  // WAR: round-A reads complete before slots 0..3 overwritten

  // ---- round B: insts 12..15 overwrite slots 0..3 ----
#pragma unroll
  for (int i = 12; i < 16; ++i) {
    const int s = i - 12;
    const int fi = s * CHUNK + (wt ^ ((s & 7) << 2));
    *reinterpret_cast<float4*>(&tile[fi]) =
        make_float4(A[i][0], A[i][1], A[i][2], A[i][3]);
  }
  lds_fence();  // RAW
  if (lane >= 48) {           // rows for insts 12..15
    const int s = i2 - 12;
#pragma unroll
    for (int j = 0; j < 16; ++j) {
      const int fi = s * CHUNK + ((f2 * 64 + 4 * j) ^ ((s & 7) << 2));
      const float4 q = *reinterpret_cast<const float4*>(&tile[fi]);
      w[4 * j + 0] = q.x; w[4 * j + 1] = q.y; w[4 * j + 2] = q.z; w[4 * j + 3] = q.w;
    }
  }

  // ---- pass 2: each lane sorts its (inst, frame) row of 64 ----
  sort_desc64(w);
  const float tau2 = sparsemax_tau(w);

  // ---- phase 3: broadcast row-taus; sources: regs (i<4) or LDS; store ----
  const int f1 = lane >> 4;   // this lane's frame
#pragma unroll
  for (int i = 0; i < N_INST; ++i) {
    const int srclane = i * 4 + f1;  // pass-2 lane holding tau for (i, f1)
    const float taui = __int_as_float(
        __builtin_amdgcn_ds_bpermute(srclane << 2, __float_as_int(tau2)));
    float4 q;
    if (i < 4) {
      q = make_float4(A[i][0], A[i][1], A[i][2], A[i][3]);  // kept in regs
    } else {
      const int s = (i < 12) ? i : (i - 12);
      const int fi = s * CHUNK + (wt ^ ((s & 7) << 2));
      q = *reinterpret_cast<const float4*>(&tile[fi]);
    }
    float4 o;
    o.x = fmaxf(q.x - taui, 0.0f);
    o.y = fmaxf(q.y - taui, 0.0f);
    o.z = fmaxf(q.z - taui, 0.0f);
    o.w = fmaxf(q.w - taui, 0.0f);
    *reinterpret_cast<float4*>(out + base + (size_t)i * T_DIM) = o;
  }
}

extern "C" void kernel_launch(void* const* d_in, const int* in_sizes, int n_in,
                              void* d_out, int out_size, void* d_ws, size_t ws_size,
                              hipStream_t stream) {
  const float* in = (const float*)d_in[0];
  float* out = (float*)d_out;
  const int grid = B_DIM * NCHUNK / WPB;  // 2048 blocks x 4 independent waves
  seq_sparsemax_kernel<<<grid, 256, 0, stream>>>(in, out);
}